// Round 6
// baseline (201.128 us; speedup 1.0000x reference)
//
#include <hip/hip_runtime.h>
#include <hip/hip_bf16.h>
#include <math.h>

#define B_   16
#define CIN  64
#define COUT 64
#define H_   128
#define W_   128
#define KK   25
#define HW   (H_ * W_)
#define XT_PLANE ((size_t)B_ * HW * 32)   // shorts per 32-channel plane (16 MiB)

typedef short  bf16x8 __attribute__((ext_vector_type(8)));
typedef short  s16x4  __attribute__((ext_vector_type(4)));
typedef float  f32x16 __attribute__((ext_vector_type(16)));
typedef float  f32x4  __attribute__((ext_vector_type(4)));
typedef float  f32x2  __attribute__((ext_vector_type(2)));

__device__ __forceinline__ short f2bs(float v) {
    __hip_bfloat16 h = __float2bfloat16(v);
    return *reinterpret_cast<short*>(&h);
}
__device__ __forceinline__ float bs2f(short s) {
    unsigned int u = ((unsigned int)(unsigned short)s) << 16;
    return __uint_as_float(u);
}

// ---------------- Kernel 0: fused weight-prep + x-prep ----------------------
// z == B_ slice (x==0, y<COUT): wprep for oc = blockIdx.y — coalesced load of
//   w[o][*][*], 25 per-tap L2 norms over cin, scatter bf16 fragments:
//   wnb2[kk][ks][tile][lane][j] = wn[oc=tile*32+(lane&31)][cin=ks*16+(lane>>5)*8+j]
// z < B_: xprep — x -> channels-last bf16 planes xt[half][b*HW+p][32ch]
//   + per-pixel ssq xsqg[b*HW+p]. LDS-transposed, coalesced both sides.
__global__ __launch_bounds__(256) void k_prep(const float* __restrict__ x,
                                              const float* __restrict__ w,
                                              short* __restrict__ xt,
                                              float* __restrict__ xsqg,
                                              short* __restrict__ wnb2) {
    const int tid = threadIdx.x;

    if (blockIdx.z == B_) {               // ---- weight-prep slice
        if (blockIdx.x != 0 || blockIdx.y >= COUT) return;
        __shared__ float wl[CIN * KK];    // [i][kk] for this o
        __shared__ float inv[KK];
        const int o = blockIdx.y;

        for (int idx = tid; idx < CIN * KK; idx += 256)
            wl[idx] = w[(size_t)o * (CIN * KK) + idx];
        __syncthreads();
        if (tid < KK) {
            float s = 0.f;
            #pragma unroll 8
            for (int i = 0; i < CIN; ++i) { float v = wl[i * KK + tid]; s += v * v; }
            inv[tid] = 1.f / fmaxf(sqrtf(s), 1e-12f);
        }
        __syncthreads();
        const int tt = o >> 5, n = o & 31;
        for (int idx = tid; idx < CIN * KK; idx += 256) {   // ci fastest
            int ci = idx & 63, kk = idx >> 6;
            int ks = ci >> 4, q = (ci >> 3) & 1, j = ci & 7;
            int l = q * 32 + n;
            wnb2[((size_t)((kk * 4 + ks) * 2 + tt) * 64 + l) * 8 + j] =
                f2bs(fabsf(wl[ci * KK + kk]) * inv[kk]);
        }
        return;
    }

    // ---- x-prep slice
    __shared__ float tile[64][65];       // +1 pad: conflict-free both phases
    __shared__ float ps[4][64];
    const int b = blockIdx.z, h = blockIdx.y, w0 = blockIdx.x * 64;

    const float* xb = x + (size_t)b * CIN * HW + h * W_ + w0;
    {
        int wl = tid & 63, c0 = tid >> 6;    // c0: 0..3 -> 16 ci each
        float sq = 0.f;
        #pragma unroll
        for (int cc = 0; cc < 16; ++cc) {
            float v = xb[(size_t)(c0 * 16 + cc) * HW + wl];   // 256B coalesced
            tile[c0 * 16 + cc][wl] = v;
            sq += v * v;
        }
        ps[c0][wl] = sq;
    }
    __syncthreads();

    const size_t pixbase = (size_t)b * HW + h * W_ + w0;
    if (tid < 64)
        xsqg[pixbase + tid] = ps[0][tid] + ps[1][tid] + ps[2][tid] + ps[3][tid];

    {
        int c8 = tid & 7;                    // 8-ci chunk: global ci = c8*8+j
        int half = c8 >> 2, sl = c8 & 3;     // plane, slot within plane
        short* dp = xt + (size_t)half * XT_PLANE;
        #pragma unroll
        for (int rep = 0; rep < 2; ++rep) {
            int p = (tid >> 3) + rep * 32;
            bf16x8 v;
            #pragma unroll
            for (int j = 0; j < 8; ++j) v[j] = f2bs(tile[c8 * 8 + j][p]);  // 2-way banks
            *(bf16x8*)&dp[(pixbase + p) * 32 + sl * 8] = v;   // contiguous 1KB/wave
        }
    }
}

// ---------------- Kernel 1: MFMA implicit-GEMM conv + cosine normalize -------
// Block: 256 thr = 4 waves; tile 8h x 32w x 64oc. Wave: 2 h-rows x 2 oc-tiles.
// cin in TWO 32-channel planes. NEW: B-fragments staged in LDS per tap with a
// 2-buffer pipeline (all 4 waves read IDENTICAL B -> load once per block, ds_read
// in loop instead of per-wave L2 loads; prefetch of tap kk+1 hides under tap kk's
// MFMAs). xin shrunk XP 40->32 via XOR chunk-swizzle (chunk ^= s&3; NC=36 = 0 mod 4
// so a0/a1 share the XOR; uniform-8 bank spread = b128 minimum) to keep the whole
// pool at 40320 B -> 4 blocks/CU with __launch_bounds__(256,4).
#define NR 12            // window rows (8 + 4 halo)
#define NC 36            // window cols (32 + 4 halo)
#define NS (NR * NC)     // 432
#define TP 264           // trans row stride in shorts

__global__ __launch_bounds__(256, 4) void k_conv(const short* __restrict__ xt,
                                                 const float* __restrict__ xsqg,
                                                 const short* __restrict__ wnb2,
                                                 __hip_bfloat16* __restrict__ t) {
    // manual LDS pool (aliased): 40320 B total
    //   [0,27648)      xin  [NS][32] shorts, chunk-swizzled
    //   [27648,35840)  bbuf [2][2048] shorts (per-tap B double buffer)
    //   [35840,37568)  s2win[NS] float
    //   [37568,39296)  soff [NS] int
    //   [39296,40320)  xsq  [256] float
    //   epilogue: trans[64][TP] = 33792 B reuses [0,33792) (xin+bbuf dead)
    __shared__ __align__(16) short pool[20160];
    short* xin   = pool;
    short* bbuf  = pool + 13824;
    float* s2win = (float*)&pool[17920];
    int*   soff  = (int*)&pool[18784];
    float* xsq   = (float*)&pool[19648];

    const int tid  = threadIdx.x;
    const int lane = tid & 63;
    const int wv   = tid >> 6;
    const int n    = lane & 31;
    const int q    = lane >> 5;
    const int b    = blockIdx.z;
    const int h0   = blockIdx.y * 8;
    const int w0   = blockIdx.x * 32;

    const size_t pixbase = (size_t)b * HW;

    // ---- reflect map + gather of precomputed per-pixel ssq
    for (int s = tid; s < NS; s += 256) {
        int r = s / NC, c = s - r * NC;
        int hh = h0 - 2 + r; hh = hh < 0 ? -hh : (hh > H_ - 1 ? 2 * (H_ - 1) - hh : hh);
        int ww = w0 - 2 + c; ww = ww < 0 ? -ww : (ww > W_ - 1 ? 2 * (W_ - 1) - ww : ww);
        int off = hh * W_ + ww;
        soff[s] = off;
        s2win[s] = xsqg[pixbase + off];
    }
    __syncthreads();

    // ---- xsq per output pixel (8 x 32): 5x5 window sum of s2win
    {
        int hr = tid >> 5, cl = tid & 31;
        float a = 0.f;
        #pragma unroll
        for (int kh = 0; kh < 5; ++kh)
            #pragma unroll
            for (int kw = 0; kw < 5; ++kw)
                a += s2win[(hr + kh) * NC + cl + kw];
        xsq[tid] = a;
    }

    f32x16 acc00, acc01, acc10, acc11;
    #pragma unroll
    for (int i = 0; i < 16; ++i) { acc00[i] = 0.f; acc01[i] = 0.f; acc10[i] = 0.f; acc11[i] = 0.f; }

    for (int half = 0; half < 2; ++half) {
        // ---- stage 12 x 36 window x 32 cin: vector copy, chunk-XOR-swizzled dest
        const short* xph = xt + (size_t)half * XT_PLANE + pixbase * 32;
        for (int i = tid; i < NS * 4; i += 256) {
            int s = i >> 2, c8 = i & 3;
            *(bf16x8*)&xin[s * 32 + ((c8 ^ (s & 3)) << 3)] =
                *(const bf16x8*)&xph[(size_t)soff[s] * 32 + c8 * 8];
        }
        // first tap's B into regs (16 B/thread covers the 4 KB tap block)
        const short* wsrc = wnb2 + half * 2048 + (size_t)tid * 8;
        bf16x8 breg = *(const bf16x8*)&wsrc[0];
        __syncthreads();                     // xin ready

        // ---- K loop: 25 taps; per tap: ds_write B -> barrier -> prefetch kk+1
        //      -> 8 MFMA from LDS. One barrier/tap is race-free with 2 buffers.
        for (int kk = 0; kk < KK; ++kk) {
            *(bf16x8*)&bbuf[(kk & 1) * 2048 + tid * 8] = breg;
            __syncthreads();
            if (kk < KK - 1) breg = *(const bf16x8*)&wsrc[(kk + 1) * 4096];
            const int kh = kk / 5, kw = kk % 5;
            const int sp0 = (2 * wv + kh) * NC + n + kw;
            const int sx = sp0 & 3;
            const short* bb = &bbuf[(kk & 1) * 2048];
            #pragma unroll
            for (int ks2 = 0; ks2 < 2; ++ks2) {
                const int cA = ((ks2 * 2 + q) ^ sx) << 3;
                bf16x8 a0 = *(const bf16x8*)&xin[sp0 * 32 + cA];
                bf16x8 a1 = *(const bf16x8*)&xin[(sp0 + NC) * 32 + cA];
                bf16x8 b0 = *(const bf16x8*)&bb[(ks2 * 2 + 0) * 512 + lane * 8];
                bf16x8 b1 = *(const bf16x8*)&bb[(ks2 * 2 + 1) * 512 + lane * 8];
                acc00 = __builtin_amdgcn_mfma_f32_32x32x16_bf16(a0, b0, acc00, 0, 0, 0);
                acc01 = __builtin_amdgcn_mfma_f32_32x32x16_bf16(a0, b1, acc01, 0, 0, 0);
                acc10 = __builtin_amdgcn_mfma_f32_32x32x16_bf16(a1, b0, acc10, 0, 0, 0);
                acc11 = __builtin_amdgcn_mfma_f32_32x32x16_bf16(a1, b1, acc11, 0, 0, 0);
            }
        }
        __syncthreads();   // compute(24) reads done; xin/bbuf free for next half
    }

    // ---- epilogue: y = acc * rsqrt(xsq); transpose via LDS; coalesced store
    short* trans = pool;
    const int hrA = 2 * wv, hrB = 2 * wv + 1;
    #pragma unroll
    for (int g4 = 0; g4 < 4; ++g4) {
        int wc0 = 8 * g4 + 4 * q;
        s16x4 v00, v01, v10, v11;
        #pragma unroll
        for (int j = 0; j < 4; ++j) {
            float ia = rsqrtf(xsq[hrA * 32 + wc0 + j] + 1e-8f);
            float ib = rsqrtf(xsq[hrB * 32 + wc0 + j] + 1e-8f);
            v00[j] = f2bs(acc00[4 * g4 + j] * ia);
            v01[j] = f2bs(acc01[4 * g4 + j] * ia);
            v10[j] = f2bs(acc10[4 * g4 + j] * ib);
            v11[j] = f2bs(acc11[4 * g4 + j] * ib);
        }
        *(s16x4*)&trans[n * TP        + hrA * 32 + wc0] = v00;
        *(s16x4*)&trans[(32 + n) * TP + hrA * 32 + wc0] = v01;
        *(s16x4*)&trans[n * TP        + hrB * 32 + wc0] = v10;
        *(s16x4*)&trans[(32 + n) * TP + hrB * 32 + wc0] = v11;
    }
    __syncthreads();

    #pragma unroll
    for (int u = tid; u < 512; u += 256) { // (oc, hr): 32 bf16 = 64 B runs
        int oc = u >> 3, hr = u & 7;
        const short* src = &trans[oc * TP + hr * 32];
        __hip_bfloat16* dst = t + ((size_t)(b * COUT + oc) * H_ + h0 + hr) * W_ + w0;
        float4 a0 = *(const float4*)(src);
        float4 a1 = *(const float4*)(src + 8);
        float4 a2 = *(const float4*)(src + 16);
        float4 a3 = *(const float4*)(src + 24);
        *(float4*)(dst)      = a0;
        *(float4*)(dst + 8)  = a1;
        *(float4*)(dst + 16) = a2;
        *(float4*)(dst + 24) = a3;
    }
}

// ---------------- Kernel 2: depthwise 5x5 DoG, zero pad, fp32 out ------------
__global__ __launch_bounds__(256) void k_dog(const __hip_bfloat16* __restrict__ t,
                                             float* __restrict__ out) {
    __shared__ float tile[36 * 136];
    __shared__ float sm_s[25];
    const int bo  = blockIdx.y;
    const int h0  = blockIdx.x * 32;
    const int tid = threadIdx.x;

    if (tid < 25) {
        const float se2 = 2.f * 1.2f * 1.2f;
        const float si2 = 2.f * 1.4f * 1.4f;
        const float twopi = 6.28318530717958647692f;
        const float ae = 1.f / (twopi * 1.2f * 1.2f);
        const float ai = 1.f / (twopi * 1.4f * 1.4f);
        const float c0 = ae - ai;
        int dx = tid / 5 - 2, dy = tid % 5 - 2;
        float r2 = (float)(dx * dx + dy * dy);
        sm_s[tid] = (ae * expf(-r2 / se2) - ai * expf(-r2 / si2)) / c0;
    }

    // interior: cols 2..129 of tile <- w 0..127, 16 B vector loads
    const __hip_bfloat16* tc = t + (size_t)bo * HW;
    for (int idx = tid; idx < 36 * 16; idx += 256) {
        int rr = idx >> 4, g = idx & 15;
        int hh = h0 - 2 + rr;
        float v[8];
        if (hh >= 0 && hh < H_) {
            bf16x8 a = *(const bf16x8*)&tc[hh * W_ + g * 8];
            #pragma unroll
            for (int j = 0; j < 8; ++j) v[j] = bs2f(a[j]);
        } else {
            #pragma unroll
            for (int j = 0; j < 8; ++j) v[j] = 0.f;
        }
        float* dst = &tile[rr * 136 + 2 + g * 8];
        *(f32x2*)(dst)     = (f32x2){v[0], v[1]};
        *(f32x4*)(dst + 2) = (f32x4){v[2], v[3], v[4], v[5]};
        *(f32x2*)(dst + 6) = (f32x2){v[6], v[7]};
    }
    // zero-pad edge columns (w = -2,-1,128,129 -> tile cols 0,1,130,131)
    if (tid < 36 * 4) {
        int rr = tid >> 2, c = tid & 3;
        tile[rr * 136 + (c < 2 ? c : 128 + c)] = 0.f;
    }
    __syncthreads();

    float smr[25];
    #pragma unroll
    for (int kk = 0; kk < 25; ++kk) smr[kk] = sm_s[kk];

    const int cq = tid & 31;
    const int r0 = tid >> 5;
    #pragma unroll
    for (int rr = 0; rr < 4; ++rr) {
        int r = r0 + 8 * rr;
        float s0 = 0.f, s1 = 0.f, s2 = 0.f, s3 = 0.f;
        #pragma unroll
        for (int kh = 0; kh < 5; ++kh) {
            const float* row = &tile[(r + kh) * 136 + cq * 4];
            f32x4 v0 = *(const f32x4*)(row);
            f32x4 v1 = *(const f32x4*)(row + 4);
            float vv[8] = { v0[0], v0[1], v0[2], v0[3], v1[0], v1[1], v1[2], v1[3] };
            #pragma unroll
            for (int kw = 0; kw < 5; ++kw) {
                float cf = smr[kh * 5 + kw];
                s0 += cf * vv[kw];
                s1 += cf * vv[kw + 1];
                s2 += cf * vv[kw + 2];
                s3 += cf * vv[kw + 3];
            }
        }
        float4 o4 = make_float4(s0, s1, s2, s3);
        *(float4*)&out[((size_t)bo * H_ + h0 + r) * W_ + cq * 4] = o4;
    }
}

// -----------------------------------------------------------------------------
extern "C" void kernel_launch(void* const* d_in, const int* in_sizes, int n_in,
                              void* d_out, int out_size, void* d_ws, size_t ws_size,
                              hipStream_t stream) {
    const float* x = (const float*)d_in[0];
    const float* w = (const float*)d_in[1];

    __hip_bfloat16* t = (__hip_bfloat16*)d_ws;    // 32 MiB intermediate

    // d_out (64 MiB) scratch layout, all fully overwritten by k_dog at the end:
    //   [0, 32 MiB)         xt: two channels-last bf16 planes
    //   [32 MiB, +1 MiB)    xsqg: per-pixel sum of x^2 over cin
    //   [64 MiB - 200 KiB)  wnb2: fragment-ordered normalized bf16 weights
    short* xt    = (short*)d_out;
    float* xsqg  = (float*)((char*)d_out + 33554432);
    short* wnb2  = (short*)((char*)d_out + (size_t)67108864 - 204800);

    dim3 gx(W_ / 64, H_, B_ + 1);    // z==B_ slice runs weight-prep
    k_prep<<<gx, 256, 0, stream>>>(x, w, xt, xsqg, wnb2);

    dim3 g2(W_ / 32, H_ / 8, B_);    // 4 x 16 x 16 = 1024 blocks
    k_conv<<<g2, 256, 0, stream>>>(xt, xsqg, wnb2, t);

    dim3 g3(H_ / 32, B_ * COUT);     // 4 x 1024 blocks
    k_dog<<<g3, 256, 0, stream>>>(t, (float*)d_out);
}

// Round 7
// 190.834 us; speedup vs baseline: 1.0539x; 1.0539x over previous
//
#include <hip/hip_runtime.h>
#include <hip/hip_bf16.h>
#include <math.h>

#define B_   16
#define CIN  64
#define COUT 64
#define H_   128
#define W_   128
#define KK   25
#define HW   (H_ * W_)
#define XT_PLANE ((size_t)B_ * HW * 32)   // shorts per 32-channel plane (16 MiB)

typedef short  bf16x8 __attribute__((ext_vector_type(8)));
typedef short  s16x4  __attribute__((ext_vector_type(4)));
typedef float  f32x16 __attribute__((ext_vector_type(16)));
typedef float  f32x4  __attribute__((ext_vector_type(4)));
typedef float  f32x2  __attribute__((ext_vector_type(2)));

__device__ __forceinline__ short f2bs(float v) {
    __hip_bfloat16 h = __float2bfloat16(v);
    return *reinterpret_cast<short*>(&h);
}
__device__ __forceinline__ float bs2f(short s) {
    unsigned int u = ((unsigned int)(unsigned short)s) << 16;
    return __uint_as_float(u);
}

// ---------------- Kernel 0: fused weight-prep + x-prep ----------------------
// z == B_ slice (x==0, y<COUT): wprep for oc = blockIdx.y — coalesced load of
//   w[o][*][*], 25 per-tap L2 norms over cin, scatter bf16 fragments:
//   wnb2[kk][ks][tile][lane][j] = wn[oc=tile*32+(lane&31)][cin=ks*16+(lane>>5)*8+j]
// z < B_: xprep — x -> channels-last bf16 planes xt[half][b*HW+p][32ch]
//   + per-pixel ssq xsqg[b*HW+p]. LDS-transposed, coalesced both sides.
__global__ __launch_bounds__(256) void k_prep(const float* __restrict__ x,
                                              const float* __restrict__ w,
                                              short* __restrict__ xt,
                                              float* __restrict__ xsqg,
                                              short* __restrict__ wnb2) {
    const int tid = threadIdx.x;

    if (blockIdx.z == B_) {               // ---- weight-prep slice
        if (blockIdx.x != 0 || blockIdx.y >= COUT) return;
        __shared__ float wl[CIN * KK];    // [i][kk] for this o
        __shared__ float inv[KK];
        const int o = blockIdx.y;

        for (int idx = tid; idx < CIN * KK; idx += 256)
            wl[idx] = w[(size_t)o * (CIN * KK) + idx];
        __syncthreads();
        if (tid < KK) {
            float s = 0.f;
            #pragma unroll 8
            for (int i = 0; i < CIN; ++i) { float v = wl[i * KK + tid]; s += v * v; }
            inv[tid] = 1.f / fmaxf(sqrtf(s), 1e-12f);
        }
        __syncthreads();
        const int tt = o >> 5, n = o & 31;
        for (int idx = tid; idx < CIN * KK; idx += 256) {   // ci fastest
            int ci = idx & 63, kk = idx >> 6;
            int ks = ci >> 4, q = (ci >> 3) & 1, j = ci & 7;
            int l = q * 32 + n;
            wnb2[((size_t)((kk * 4 + ks) * 2 + tt) * 64 + l) * 8 + j] =
                f2bs(fabsf(wl[ci * KK + kk]) * inv[kk]);
        }
        return;
    }

    // ---- x-prep slice
    __shared__ float tile[64][65];       // +1 pad: conflict-free both phases
    __shared__ float ps[4][64];
    const int b = blockIdx.z, h = blockIdx.y, w0 = blockIdx.x * 64;

    const float* xb = x + (size_t)b * CIN * HW + h * W_ + w0;
    {
        int wl = tid & 63, c0 = tid >> 6;    // c0: 0..3 -> 16 ci each
        float sq = 0.f;
        #pragma unroll
        for (int cc = 0; cc < 16; ++cc) {
            float v = xb[(size_t)(c0 * 16 + cc) * HW + wl];   // 256B coalesced
            tile[c0 * 16 + cc][wl] = v;
            sq += v * v;
        }
        ps[c0][wl] = sq;
    }
    __syncthreads();

    const size_t pixbase = (size_t)b * HW + h * W_ + w0;
    if (tid < 64)
        xsqg[pixbase + tid] = ps[0][tid] + ps[1][tid] + ps[2][tid] + ps[3][tid];

    {
        int c8 = tid & 7;                    // 8-ci chunk: global ci = c8*8+j
        int half = c8 >> 2, sl = c8 & 3;     // plane, slot within plane
        short* dp = xt + (size_t)half * XT_PLANE;
        #pragma unroll
        for (int rep = 0; rep < 2; ++rep) {
            int p = (tid >> 3) + rep * 32;
            bf16x8 v;
            #pragma unroll
            for (int j = 0; j < 8; ++j) v[j] = f2bs(tile[c8 * 8 + j][p]);  // 2-way banks
            *(bf16x8*)&dp[(pixbase + p) * 32 + sl * 8] = v;   // contiguous 1KB/wave
        }
    }
}

// ---------------- Kernel 1: MFMA implicit-GEMM conv + cosine normalize -------
// EXACT R5 body (proven 68.3 us): B-fragments direct from global (L2-resident,
// compiler-scheduled), XP=40 layout (0.70M bank conflicts), 2 barriers/half.
// R6's LDS B-dbuf regressed (10.1M conflicts, tap barriers) — reverted.
#define XP 40            // xin cin-stride in shorts (80B: 16B-aligned)
#define NR 12            // window rows (8 + 4 halo)
#define NC 36            // window cols (32 + 4 halo)
#define NS (NR * NC)     // 432
#define TP 264           // trans row stride in shorts

__global__ __launch_bounds__(256, 4) void k_conv(const short* __restrict__ xt,
                                                 const float* __restrict__ xsqg,
                                                 const short* __restrict__ wnb2,
                                                 __hip_bfloat16* __restrict__ t) {
    __shared__ short xin[NS * XP];        // 34560 B; reused as trans[64][TP] (33792 B)
    __shared__ float s2win[NS];           // 1728 B
    __shared__ int   soff[NS];            // 1728 B  reflect-resolved pixel offsets
    __shared__ float xsq[256];            // 1024 B  (39040 B total)

    const int tid  = threadIdx.x;
    const int lane = tid & 63;
    const int wv   = tid >> 6;
    const int n    = lane & 31;
    const int q    = lane >> 5;
    const int b    = blockIdx.z;
    const int h0   = blockIdx.y * 8;
    const int w0   = blockIdx.x * 32;

    const size_t pixbase = (size_t)b * HW;

    // ---- reflect map + gather of precomputed per-pixel ssq
    for (int s = tid; s < NS; s += 256) {
        int r = s / NC, c = s - r * NC;
        int hh = h0 - 2 + r; hh = hh < 0 ? -hh : (hh > H_ - 1 ? 2 * (H_ - 1) - hh : hh);
        int ww = w0 - 2 + c; ww = ww < 0 ? -ww : (ww > W_ - 1 ? 2 * (W_ - 1) - ww : ww);
        int off = hh * W_ + ww;
        soff[s] = off;
        s2win[s] = xsqg[pixbase + off];
    }
    __syncthreads();

    // ---- xsq per output pixel (8 x 32): 5x5 window sum of s2win
    {
        int hr = tid >> 5, cl = tid & 31;
        float a = 0.f;
        #pragma unroll
        for (int kh = 0; kh < 5; ++kh)
            #pragma unroll
            for (int kw = 0; kw < 5; ++kw)
                a += s2win[(hr + kh) * NC + cl + kw];
        xsq[tid] = a;
    }

    const short* wb = wnb2 + (size_t)lane * 8;   // per-lane fragment base

    f32x16 acc00, acc01, acc10, acc11;
    #pragma unroll
    for (int i = 0; i < 16; ++i) { acc00[i] = 0.f; acc01[i] = 0.f; acc10[i] = 0.f; acc11[i] = 0.f; }

    #pragma unroll
    for (int half = 0; half < 2; ++half) {
        // ---- stage 12 x 36 window x 32 cin: pure vector copy (16B/lane)
        const short* xph = xt + (size_t)half * XT_PLANE + pixbase * 32;
        for (int i = tid; i < NS * 4; i += 256) {
            int s = i >> 2, c8 = i & 3;
            *(bf16x8*)&xin[s * 32 + c8 * 8 + (s * 8 & 2047) * 0 + s * (XP - 32)] =
                *(const bf16x8*)&xph[(size_t)soff[s] * 32 + c8 * 8];
        }
        __syncthreads();

        // ---- K loop: 25 taps x 32 cin for this half, barrier-free inside
        #pragma unroll 5
        for (int kk = 0; kk < KK; ++kk) {
            const int kh = kk / 5, kw = kk % 5;
            const int sp0 = (2 * wv + kh) * NC + n + kw;
            #pragma unroll
            for (int ks2 = 0; ks2 < 2; ++ks2) {
                const int ks = half * 2 + ks2;      // global 16-cin chunk for B
                const int ko = ks2 * 16 + q * 8;    // local offset inside xin half
                bf16x8 a0 = *(const bf16x8*)&xin[sp0 * XP + ko];
                bf16x8 a1 = *(const bf16x8*)&xin[(sp0 + NC) * XP + ko];
                bf16x8 b0 = *(const bf16x8*)&wb[(size_t)((kk * 4 + ks) * 2 + 0) * 512];
                bf16x8 b1 = *(const bf16x8*)&wb[(size_t)((kk * 4 + ks) * 2 + 1) * 512];
                acc00 = __builtin_amdgcn_mfma_f32_32x32x16_bf16(a0, b0, acc00, 0, 0, 0);
                acc01 = __builtin_amdgcn_mfma_f32_32x32x16_bf16(a0, b1, acc01, 0, 0, 0);
                acc10 = __builtin_amdgcn_mfma_f32_32x32x16_bf16(a1, b0, acc10, 0, 0, 0);
                acc11 = __builtin_amdgcn_mfma_f32_32x32x16_bf16(a1, b1, acc11, 0, 0, 0);
            }
        }
        __syncthreads();   // K-loop reads of xin done; xin free for next half
    }

    // ---- epilogue: y = acc * rsqrt(xsq); transpose via LDS; coalesced store
    short* trans = xin;
    const int hrA = 2 * wv, hrB = 2 * wv + 1;
    #pragma unroll
    for (int g4 = 0; g4 < 4; ++g4) {
        int wc0 = 8 * g4 + 4 * q;
        s16x4 v00, v01, v10, v11;
        #pragma unroll
        for (int j = 0; j < 4; ++j) {
            float ia = rsqrtf(xsq[hrA * 32 + wc0 + j] + 1e-8f);
            float ib = rsqrtf(xsq[hrB * 32 + wc0 + j] + 1e-8f);
            v00[j] = f2bs(acc00[4 * g4 + j] * ia);
            v01[j] = f2bs(acc01[4 * g4 + j] * ia);
            v10[j] = f2bs(acc10[4 * g4 + j] * ib);
            v11[j] = f2bs(acc11[4 * g4 + j] * ib);
        }
        *(s16x4*)&trans[n * TP        + hrA * 32 + wc0] = v00;
        *(s16x4*)&trans[(32 + n) * TP + hrA * 32 + wc0] = v01;
        *(s16x4*)&trans[n * TP        + hrB * 32 + wc0] = v10;
        *(s16x4*)&trans[(32 + n) * TP + hrB * 32 + wc0] = v11;
    }
    __syncthreads();

    #pragma unroll
    for (int u = tid; u < 512; u += 256) { // (oc, hr): 32 bf16 = 64 B runs
        int oc = u >> 3, hr = u & 7;
        const short* src = &trans[oc * TP + hr * 32];
        __hip_bfloat16* dst = t + ((size_t)(b * COUT + oc) * H_ + h0 + hr) * W_ + w0;
        float4 a0 = *(const float4*)(src);
        float4 a1 = *(const float4*)(src + 8);
        float4 a2 = *(const float4*)(src + 16);
        float4 a3 = *(const float4*)(src + 24);
        *(float4*)(dst)      = a0;
        *(float4*)(dst + 8)  = a1;
        *(float4*)(dst + 16) = a2;
        *(float4*)(dst + 24) = a3;
    }
}

// ---------------- Kernel 2: depthwise 5x5 DoG, zero pad, fp32 out ------------
// RESTRUCTURED: 64-row tiles (grid 2048 vs 4096): halo overfetch 12.5% -> 6%,
// half the per-block staging/barrier overhead. LDS 68*132*4 = 35904 B -> still
// 4 blocks/CU. Inner compute loop identical to previous version.
__global__ __launch_bounds__(256) void k_dog(const __hip_bfloat16* __restrict__ t,
                                             float* __restrict__ out) {
    __shared__ float tile[68 * 132];
    __shared__ float sm_s[25];
    const int bo  = blockIdx.y;
    const int h0  = blockIdx.x * 64;
    const int tid = threadIdx.x;

    if (tid < 25) {
        const float se2 = 2.f * 1.2f * 1.2f;
        const float si2 = 2.f * 1.4f * 1.4f;
        const float twopi = 6.28318530717958647692f;
        const float ae = 1.f / (twopi * 1.2f * 1.2f);
        const float ai = 1.f / (twopi * 1.4f * 1.4f);
        const float c0 = ae - ai;
        int dx = tid / 5 - 2, dy = tid % 5 - 2;
        float r2 = (float)(dx * dx + dy * dy);
        sm_s[tid] = (ae * expf(-r2 / se2) - ai * expf(-r2 / si2)) / c0;
    }

    // interior: cols 2..129 of tile <- w 0..127, 16 B vector loads
    const __hip_bfloat16* tc = t + (size_t)bo * HW;
    for (int idx = tid; idx < 68 * 16; idx += 256) {
        int rr = idx >> 4, g = idx & 15;
        int hh = h0 - 2 + rr;
        float v[8];
        if (hh >= 0 && hh < H_) {
            bf16x8 a = *(const bf16x8*)&tc[hh * W_ + g * 8];
            #pragma unroll
            for (int j = 0; j < 8; ++j) v[j] = bs2f(a[j]);
        } else {
            #pragma unroll
            for (int j = 0; j < 8; ++j) v[j] = 0.f;
        }
        float* dst = &tile[rr * 132 + 2 + g * 8];
        *(f32x2*)(dst)     = (f32x2){v[0], v[1]};
        *(f32x4*)(dst + 2) = (f32x4){v[2], v[3], v[4], v[5]};
        *(f32x2*)(dst + 6) = (f32x2){v[6], v[7]};
    }
    // zero-pad edge columns (w = -2,-1,128,129 -> tile cols 0,1,130,131)
    for (int idx = tid; idx < 68 * 4; idx += 256) {
        int rr = idx >> 2, c = idx & 3;
        tile[rr * 132 + (c < 2 ? c : 128 + c)] = 0.f;
    }
    __syncthreads();

    float smr[25];
    #pragma unroll
    for (int kk = 0; kk < 25; ++kk) smr[kk] = sm_s[kk];

    const int cq = tid & 31;
    const int r0 = tid >> 5;
    #pragma unroll
    for (int rr = 0; rr < 8; ++rr) {
        int r = r0 + 8 * rr;
        float s0 = 0.f, s1 = 0.f, s2 = 0.f, s3 = 0.f;
        #pragma unroll
        for (int kh = 0; kh < 5; ++kh) {
            const float* row = &tile[(r + kh) * 132 + cq * 4];
            f32x4 v0 = *(const f32x4*)(row);
            f32x4 v1 = *(const f32x4*)(row + 4);
            float vv[8] = { v0[0], v0[1], v0[2], v0[3], v1[0], v1[1], v1[2], v1[3] };
            #pragma unroll
            for (int kw = 0; kw < 5; ++kw) {
                float cf = smr[kh * 5 + kw];
                s0 += cf * vv[kw];
                s1 += cf * vv[kw + 1];
                s2 += cf * vv[kw + 2];
                s3 += cf * vv[kw + 3];
            }
        }
        float4 o4 = make_float4(s0, s1, s2, s3);
        *(float4*)&out[((size_t)bo * H_ + h0 + r) * W_ + cq * 4] = o4;
    }
}

// -----------------------------------------------------------------------------
extern "C" void kernel_launch(void* const* d_in, const int* in_sizes, int n_in,
                              void* d_out, int out_size, void* d_ws, size_t ws_size,
                              hipStream_t stream) {
    const float* x = (const float*)d_in[0];
    const float* w = (const float*)d_in[1];

    __hip_bfloat16* t = (__hip_bfloat16*)d_ws;    // 32 MiB intermediate

    // d_out (64 MiB) scratch layout, all fully overwritten by k_dog at the end:
    //   [0, 32 MiB)         xt: two channels-last bf16 planes
    //   [32 MiB, +1 MiB)    xsqg: per-pixel sum of x^2 over cin
    //   [64 MiB - 200 KiB)  wnb2: fragment-ordered normalized bf16 weights
    short* xt    = (short*)d_out;
    float* xsqg  = (float*)((char*)d_out + 33554432);
    short* wnb2  = (short*)((char*)d_out + (size_t)67108864 - 204800);

    dim3 gx(W_ / 64, H_, B_ + 1);    // z==B_ slice runs weight-prep
    k_prep<<<gx, 256, 0, stream>>>(x, w, xt, xsqg, wnb2);

    dim3 g2(W_ / 32, H_ / 8, B_);    // 4 x 16 x 16 = 1024 blocks
    k_conv<<<g2, 256, 0, stream>>>(xt, xsqg, wnb2, t);

    dim3 g3(H_ / 64, B_ * COUT);     // 2 x 1024 blocks
    k_dog<<<g3, 256, 0, stream>>>(t, (float*)d_out);
}

// Round 8
// 189.896 us; speedup vs baseline: 1.0591x; 1.0049x over previous
//
#include <hip/hip_runtime.h>
#include <hip/hip_bf16.h>
#include <math.h>

#define B_   16
#define CIN  64
#define COUT 64
#define H_   128
#define W_   128
#define KK   25
#define HW   (H_ * W_)
#define XT_PLANE ((size_t)B_ * HW * 32)   // shorts per 32-channel plane (16 MiB)
#define WTS ((size_t)COUT * H_ * 32)      // t2 w-tile panel stride in shorts

typedef short  bf16x8 __attribute__((ext_vector_type(8)));
typedef short  s16x4  __attribute__((ext_vector_type(4)));
typedef float  f32x16 __attribute__((ext_vector_type(16)));
typedef float  f32x4  __attribute__((ext_vector_type(4)));
typedef float  f32x2  __attribute__((ext_vector_type(2)));

__device__ __forceinline__ short f2bs(float v) {
    __hip_bfloat16 h = __float2bfloat16(v);
    return *reinterpret_cast<short*>(&h);
}
__device__ __forceinline__ float bs2f(short s) {
    unsigned int u = ((unsigned int)(unsigned short)s) << 16;
    return __uint_as_float(u);
}

// ---------------- Kernel 0: fused weight-prep + x-prep ----------------------
// z == B_ slice (x==0, y<COUT): wprep for oc = blockIdx.y — coalesced load of
//   w[o][*][*], 25 per-tap L2 norms over cin, scatter bf16 fragments:
//   wnb2[kk][ks][tile][lane][j] = wn[oc=tile*32+(lane&31)][cin=ks*16+(lane>>5)*8+j]
// z < B_: xprep — x -> channels-last bf16 planes xt[half][b*HW+p][32ch]
//   + per-pixel ssq xsqg[b*HW+p]. NEW: f32x4 vectorized x loads (16B/lane);
//   ssq folded into the LDS transpose pass (ps[8][64]).
__global__ __launch_bounds__(256) void k_prep(const float* __restrict__ x,
                                              const float* __restrict__ w,
                                              short* __restrict__ xt,
                                              float* __restrict__ xsqg,
                                              short* __restrict__ wnb2) {
    const int tid = threadIdx.x;

    if (blockIdx.z == B_) {               // ---- weight-prep slice
        if (blockIdx.x != 0 || blockIdx.y >= COUT) return;
        __shared__ float wl[CIN * KK];    // [i][kk] for this o
        __shared__ float inv[KK];
        const int o = blockIdx.y;

        for (int idx = tid; idx < CIN * KK; idx += 256)
            wl[idx] = w[(size_t)o * (CIN * KK) + idx];
        __syncthreads();
        if (tid < KK) {
            float s = 0.f;
            #pragma unroll 8
            for (int i = 0; i < CIN; ++i) { float v = wl[i * KK + tid]; s += v * v; }
            inv[tid] = 1.f / fmaxf(sqrtf(s), 1e-12f);
        }
        __syncthreads();
        const int tt = o >> 5, n = o & 31;
        for (int idx = tid; idx < CIN * KK; idx += 256) {   // ci fastest
            int ci = idx & 63, kk = idx >> 6;
            int ks = ci >> 4, q = (ci >> 3) & 1, j = ci & 7;
            int l = q * 32 + n;
            wnb2[((size_t)((kk * 4 + ks) * 2 + tt) * 64 + l) * 8 + j] =
                f2bs(fabsf(wl[ci * KK + kk]) * inv[kk]);
        }
        return;
    }

    // ---- x-prep slice
    __shared__ float tile[64][65];       // +1 pad: conflict-free both phases
    __shared__ float ps[8][64];
    const int b = blockIdx.z, h = blockIdx.y, w0 = blockIdx.x * 64;

    const float* xb = x + (size_t)b * CIN * HW + h * W_ + w0;
    {
        int c4 = tid & 15, g = tid >> 4;     // w-chunk 4*c4, ci-group 4*g
        #pragma unroll
        for (int k = 0; k < 4; ++k) {
            int ci = g * 4 + k;
            *(f32x4*)&tile[ci][c4 * 4] =
                *(const f32x4*)&xb[(size_t)ci * HW + c4 * 4];   // 256B/16-lane run
        }
    }
    __syncthreads();

    const size_t pixbase = (size_t)b * HW + h * W_ + w0;
    {
        int c8 = tid & 7;                    // 8-ci chunk: global ci = c8*8+j
        int half = c8 >> 2, sl = c8 & 3;     // plane, slot within plane
        short* dp = xt + (size_t)half * XT_PLANE;
        #pragma unroll
        for (int rep = 0; rep < 2; ++rep) {
            int p = (tid >> 3) + rep * 32;
            bf16x8 v; float sq = 0.f;
            #pragma unroll
            for (int j = 0; j < 8; ++j) {
                float f = tile[c8 * 8 + j][p];   // 2-way banks (free)
                sq += f * f;
                v[j] = f2bs(f);
            }
            ps[c8][p] = sq;                      // unique (c8,p) per rep
            *(bf16x8*)&dp[(pixbase + p) * 32 + sl * 8] = v;   // contiguous 1KB/wave
        }
    }
    __syncthreads();
    if (tid < 64) {
        float a = 0.f;
        #pragma unroll
        for (int c8 = 0; c8 < 8; ++c8) a += ps[c8][tid];
        xsqg[pixbase + tid] = a;
    }
}

// ---------------- Kernel 1: MFMA implicit-GEMM conv + cosine normalize -------
// EXACT R5/R7 compute body (proven 68 us). NEW: t stored w-tile-major
// t2[(b*4+wt)][oc][h][32w] so each block's epilogue writes fully-contiguous
// 512B-aligned runs (full 128B lines; was 64B partial lines shared with the
// neighboring w-tile block -> 44MB WRITE_SIZE for a 32MB buffer).
#define XP 40            // xin cin-stride in shorts (80B: 16B-aligned)
#define NR 12            // window rows (8 + 4 halo)
#define NC 36            // window cols (32 + 4 halo)
#define NS (NR * NC)     // 432
#define TP 264           // trans row stride in shorts

__global__ __launch_bounds__(256, 4) void k_conv(const short* __restrict__ xt,
                                                 const float* __restrict__ xsqg,
                                                 const short* __restrict__ wnb2,
                                                 short* __restrict__ t2) {
    __shared__ short xin[NS * XP];        // 34560 B; reused as trans[64][TP] (33792 B)
    __shared__ float s2win[NS];           // 1728 B
    __shared__ int   soff[NS];            // 1728 B  reflect-resolved pixel offsets
    __shared__ float xsq[256];            // 1024 B  (39040 B total)

    const int tid  = threadIdx.x;
    const int lane = tid & 63;
    const int wv   = tid >> 6;
    const int n    = lane & 31;
    const int q    = lane >> 5;
    const int b    = blockIdx.z;
    const int h0   = blockIdx.y * 8;
    const int wt   = blockIdx.x;          // w-tile index (w0 = wt*32)
    const int w0   = wt * 32;

    const size_t pixbase = (size_t)b * HW;

    // ---- reflect map + gather of precomputed per-pixel ssq
    for (int s = tid; s < NS; s += 256) {
        int r = s / NC, c = s - r * NC;
        int hh = h0 - 2 + r; hh = hh < 0 ? -hh : (hh > H_ - 1 ? 2 * (H_ - 1) - hh : hh);
        int ww = w0 - 2 + c; ww = ww < 0 ? -ww : (ww > W_ - 1 ? 2 * (W_ - 1) - ww : ww);
        int off = hh * W_ + ww;
        soff[s] = off;
        s2win[s] = xsqg[pixbase + off];
    }
    __syncthreads();

    // ---- xsq per output pixel (8 x 32): 5x5 window sum of s2win
    {
        int hr = tid >> 5, cl = tid & 31;
        float a = 0.f;
        #pragma unroll
        for (int kh = 0; kh < 5; ++kh)
            #pragma unroll
            for (int kw = 0; kw < 5; ++kw)
                a += s2win[(hr + kh) * NC + cl + kw];
        xsq[tid] = a;
    }

    const short* wb = wnb2 + (size_t)lane * 8;   // per-lane fragment base

    f32x16 acc00, acc01, acc10, acc11;
    #pragma unroll
    for (int i = 0; i < 16; ++i) { acc00[i] = 0.f; acc01[i] = 0.f; acc10[i] = 0.f; acc11[i] = 0.f; }

    #pragma unroll
    for (int half = 0; half < 2; ++half) {
        // ---- stage 12 x 36 window x 32 cin: pure vector copy (16B/lane)
        const short* xph = xt + (size_t)half * XT_PLANE + pixbase * 32;
        for (int i = tid; i < NS * 4; i += 256) {
            int s = i >> 2, c8 = i & 3;
            *(bf16x8*)&xin[s * XP + c8 * 8] =
                *(const bf16x8*)&xph[(size_t)soff[s] * 32 + c8 * 8];
        }
        __syncthreads();

        // ---- K loop: 25 taps x 32 cin for this half, barrier-free inside
        #pragma unroll 5
        for (int kk = 0; kk < KK; ++kk) {
            const int kh = kk / 5, kw = kk % 5;
            const int sp0 = (2 * wv + kh) * NC + n + kw;
            #pragma unroll
            for (int ks2 = 0; ks2 < 2; ++ks2) {
                const int ks = half * 2 + ks2;      // global 16-cin chunk for B
                const int ko = ks2 * 16 + q * 8;    // local offset inside xin half
                bf16x8 a0 = *(const bf16x8*)&xin[sp0 * XP + ko];
                bf16x8 a1 = *(const bf16x8*)&xin[(sp0 + NC) * XP + ko];
                bf16x8 b0 = *(const bf16x8*)&wb[(size_t)((kk * 4 + ks) * 2 + 0) * 512];
                bf16x8 b1 = *(const bf16x8*)&wb[(size_t)((kk * 4 + ks) * 2 + 1) * 512];
                acc00 = __builtin_amdgcn_mfma_f32_32x32x16_bf16(a0, b0, acc00, 0, 0, 0);
                acc01 = __builtin_amdgcn_mfma_f32_32x32x16_bf16(a0, b1, acc01, 0, 0, 0);
                acc10 = __builtin_amdgcn_mfma_f32_32x32x16_bf16(a1, b0, acc10, 0, 0, 0);
                acc11 = __builtin_amdgcn_mfma_f32_32x32x16_bf16(a1, b1, acc11, 0, 0, 0);
            }
        }
        __syncthreads();   // K-loop reads of xin done; xin free for next half
    }

    // ---- epilogue: y = acc * rsqrt(xsq); transpose via LDS; full-line store
    short* trans = xin;
    const int hrA = 2 * wv, hrB = 2 * wv + 1;
    #pragma unroll
    for (int g4 = 0; g4 < 4; ++g4) {
        int wc0 = 8 * g4 + 4 * q;
        s16x4 v00, v01, v10, v11;
        #pragma unroll
        for (int j = 0; j < 4; ++j) {
            float ia = rsqrtf(xsq[hrA * 32 + wc0 + j] + 1e-8f);
            float ib = rsqrtf(xsq[hrB * 32 + wc0 + j] + 1e-8f);
            v00[j] = f2bs(acc00[4 * g4 + j] * ia);
            v01[j] = f2bs(acc01[4 * g4 + j] * ia);
            v10[j] = f2bs(acc10[4 * g4 + j] * ib);
            v11[j] = f2bs(acc11[4 * g4 + j] * ib);
        }
        *(s16x4*)&trans[n * TP        + hrA * 32 + wc0] = v00;
        *(s16x4*)&trans[(32 + n) * TP + hrA * 32 + wc0] = v01;
        *(s16x4*)&trans[n * TP        + hrB * 32 + wc0] = v10;
        *(s16x4*)&trans[(32 + n) * TP + hrB * 32 + wc0] = v11;
    }
    __syncthreads();

    short* tbase = t2 + ((size_t)(b * 4 + wt) * COUT) * (H_ * 32);
    #pragma unroll
    for (int u = tid; u < 512; u += 256) { // (oc, hr): 64B contiguous runs
        int oc = u >> 3, hr = u & 7;
        const short* src = &trans[oc * TP + hr * 32];
        short* dst = tbase + ((size_t)oc * H_ + h0 + hr) * 32;
        float4 a0 = *(const float4*)(src);
        float4 a1 = *(const float4*)(src + 8);
        float4 a2 = *(const float4*)(src + 16);
        float4 a3 = *(const float4*)(src + 24);
        *(float4*)(dst)      = a0;
        *(float4*)(dst + 8)  = a1;
        *(float4*)(dst + 16) = a2;
        *(float4*)(dst + 24) = a3;
    }
}

// ---------------- Kernel 2: depthwise 5x5 DoG, zero pad, fp32 out ------------
// 64-row tiles; reads the w-tile-major t2 layout (4 x 64B gathers per row,
// 64B-granule aligned). Compute loop unchanged.
__global__ __launch_bounds__(256) void k_dog(const short* __restrict__ t2,
                                             float* __restrict__ out) {
    __shared__ float tile[68 * 132];
    __shared__ float sm_s[25];
    const int bo  = blockIdx.y;
    const int h0  = blockIdx.x * 64;
    const int tid = threadIdx.x;

    if (tid < 25) {
        const float se2 = 2.f * 1.2f * 1.2f;
        const float si2 = 2.f * 1.4f * 1.4f;
        const float twopi = 6.28318530717958647692f;
        const float ae = 1.f / (twopi * 1.2f * 1.2f);
        const float ai = 1.f / (twopi * 1.4f * 1.4f);
        const float c0 = ae - ai;
        int dx = tid / 5 - 2, dy = tid % 5 - 2;
        float r2 = (float)(dx * dx + dy * dy);
        sm_s[tid] = (ae * expf(-r2 / se2) - ai * expf(-r2 / si2)) / c0;
    }

    // interior: cols 2..129 of tile <- w 0..127
    const int bb = bo >> 6, oc = bo & 63;
    const short* base = t2 + ((size_t)(bb * 4) * COUT + oc) * (H_ * 32);
    for (int idx = tid; idx < 68 * 16; idx += 256) {
        int rr = idx >> 4, g = idx & 15;
        int hh = h0 - 2 + rr;
        float v[8];
        if (hh >= 0 && hh < H_) {
            int wtile = g >> 2, c = g & 3;
            bf16x8 a = *(const bf16x8*)&base[(size_t)wtile * WTS + (size_t)hh * 32 + c * 8];
            #pragma unroll
            for (int j = 0; j < 8; ++j) v[j] = bs2f(a[j]);
        } else {
            #pragma unroll
            for (int j = 0; j < 8; ++j) v[j] = 0.f;
        }
        float* dst = &tile[rr * 132 + 2 + g * 8];
        *(f32x2*)(dst)     = (f32x2){v[0], v[1]};
        *(f32x4*)(dst + 2) = (f32x4){v[2], v[3], v[4], v[5]};
        *(f32x2*)(dst + 6) = (f32x2){v[6], v[7]};
    }
    // zero-pad edge columns (w = -2,-1,128,129 -> tile cols 0,1,130,131)
    for (int idx = tid; idx < 68 * 4; idx += 256) {
        int rr = idx >> 2, c = idx & 3;
        tile[rr * 132 + (c < 2 ? c : 128 + c)] = 0.f;
    }
    __syncthreads();

    float smr[25];
    #pragma unroll
    for (int kk = 0; kk < 25; ++kk) smr[kk] = sm_s[kk];

    const int cq = tid & 31;
    const int r0 = tid >> 5;
    #pragma unroll
    for (int rr = 0; rr < 8; ++rr) {
        int r = r0 + 8 * rr;
        float s0 = 0.f, s1 = 0.f, s2 = 0.f, s3 = 0.f;
        #pragma unroll
        for (int kh = 0; kh < 5; ++kh) {
            const float* row = &tile[(r + kh) * 132 + cq * 4];
            f32x4 v0 = *(const f32x4*)(row);
            f32x4 v1 = *(const f32x4*)(row + 4);
            float vv[8] = { v0[0], v0[1], v0[2], v0[3], v1[0], v1[1], v1[2], v1[3] };
            #pragma unroll
            for (int kw = 0; kw < 5; ++kw) {
                float cf = smr[kh * 5 + kw];
                s0 += cf * vv[kw];
                s1 += cf * vv[kw + 1];
                s2 += cf * vv[kw + 2];
                s3 += cf * vv[kw + 3];
            }
        }
        float4 o4 = make_float4(s0, s1, s2, s3);
        *(float4*)&out[((size_t)bo * H_ + h0 + r) * W_ + cq * 4] = o4;
    }
}

// -----------------------------------------------------------------------------
extern "C" void kernel_launch(void* const* d_in, const int* in_sizes, int n_in,
                              void* d_out, int out_size, void* d_ws, size_t ws_size,
                              hipStream_t stream) {
    const float* x = (const float*)d_in[0];
    const float* w = (const float*)d_in[1];

    short* t2 = (short*)d_ws;    // 32 MiB w-tile-major intermediate

    // d_out (64 MiB) scratch layout, all fully overwritten by k_dog at the end:
    //   [0, 32 MiB)         xt: two channels-last bf16 planes
    //   [32 MiB, +1 MiB)    xsqg: per-pixel sum of x^2 over cin
    //   [64 MiB - 200 KiB)  wnb2: fragment-ordered normalized bf16 weights
    short* xt    = (short*)d_out;
    float* xsqg  = (float*)((char*)d_out + 33554432);
    short* wnb2  = (short*)((char*)d_out + (size_t)67108864 - 204800);

    dim3 gx(W_ / 64, H_, B_ + 1);    // z==B_ slice runs weight-prep
    k_prep<<<gx, 256, 0, stream>>>(x, w, xt, xsqg, wnb2);

    dim3 g2(W_ / 32, H_ / 8, B_);    // 4 x 16 x 16 = 1024 blocks
    k_conv<<<g2, 256, 0, stream>>>(xt, xsqg, wnb2, t2);

    dim3 g3(H_ / 64, B_ * COUT);     // 2 x 1024 blocks
    k_dog<<<g3, 256, 0, stream>>>(t2, (float*)d_out);
}